// Round 1
// baseline (365.966 us; speedup 1.0000x reference)
//
#include <hip/hip_runtime.h>
#include <cstddef>

typedef __attribute__((ext_vector_type(8))) short short8;
typedef __attribute__((ext_vector_type(4))) float f32x4;

#define WC_CONST 0.2357022603955158f   // sqrt(2/(9*4))
#define WL_CONST 0.5773502691896258f   // sqrt(1/3)

__device__ __forceinline__ unsigned short rne_bf16(float f) {
  unsigned int u = __float_as_uint(f);
  u += 0x7fffu + ((u >> 16) & 1u);
  return (unsigned short)(u >> 16);
}

// ---------------- concat projection weights into [384][1152] ----------------
__global__ __launch_bounds__(256) void concat_w_kernel(
    const float* __restrict__ Wq, const float* __restrict__ Wk, const float* __restrict__ Wv,
    const float* __restrict__ Wqp, const float* __restrict__ Wkp, const float* __restrict__ Wvp,
    float* __restrict__ Wcat) {
  int idx = blockIdx.x * 256 + threadIdx.x;
  if (idx >= 384 * 1152) return;
  int k = idx / 1152, c = idx % 1152;
  float v;
  if (c < 192)       v = Wq [k*192 + c];
  else if (c < 384)  v = Wk [k*192 + (c-192)];
  else if (c < 576)  v = Wv [k*192 + (c-384)];
  else if (c < 720)  v = Wqp[k*144 + (c-576)];
  else if (c < 864)  v = Wkp[k*144 + (c-720)];
  else               v = Wvp[k*288 + (c-864)];
  Wcat[idx] = v;
}

// ---------------- generic fp32 tiled GEMM, 64x64 tile, split-K ----------------
// A: MxK row-major, B: KxN row-major, Cp: [gridDim.z][M][N] partials
__global__ __launch_bounds__(256) void gemm64_kernel(
    const float* __restrict__ Amat, const float* __restrict__ Bmat, float* __restrict__ Cp,
    int M, int N, int K, int ksl) {
  __shared__ float As[16][68];
  __shared__ float Bs[16][68];
  int t = threadIdx.x;
  int bn = blockIdx.x, bm = blockIdx.y, bz = blockIdx.z;
  int k0 = bz * ksl;
  int tr = t >> 4, tc = t & 15;
  int lm = t >> 2, lk4 = (t & 3) << 2;
  int lkb = t >> 4, lnq = (t & 15) << 2;
  const float* Ab = Amat + (size_t)(bm*64 + lm) * K;
  const float* Bb = Bmat + bn*64 + lnq;
  float acc[4][4];
  #pragma unroll
  for (int a2 = 0; a2 < 4; a2++)
    #pragma unroll
    for (int b2 = 0; b2 < 4; b2++) acc[a2][b2] = 0.f;

  for (int k = k0; k < k0 + ksl; k += 16) {
    float4 av = *(const float4*)(Ab + k + lk4);
    float4 bv = *(const float4*)(Bb + (size_t)(k + lkb) * N);
    As[lk4+0][lm] = av.x; As[lk4+1][lm] = av.y; As[lk4+2][lm] = av.z; As[lk4+3][lm] = av.w;
    *(float4*)&Bs[lkb][lnq] = bv;
    __syncthreads();
    #pragma unroll
    for (int kk = 0; kk < 16; kk++) {
      float4 a4 = *(const float4*)&As[kk][tr << 2];
      float4 b4 = *(const float4*)&Bs[kk][tc << 2];
      float ar[4] = {a4.x, a4.y, a4.z, a4.w};
      float br[4] = {b4.x, b4.y, b4.z, b4.w};
      #pragma unroll
      for (int a2 = 0; a2 < 4; a2++)
        #pragma unroll
        for (int b2 = 0; b2 < 4; b2++) acc[a2][b2] += ar[a2] * br[b2];
    }
    __syncthreads();
  }
  float* Cb = Cp + (size_t)bz * M * N + (size_t)(bm*64 + (tr << 2)) * N + bn*64 + (tc << 2);
  #pragma unroll
  for (int r = 0; r < 4; r++) {
    float4 o = {acc[r][0], acc[r][1], acc[r][2], acc[r][3]};
    *(float4*)(Cb + (size_t)r * N) = o;
  }
}

// ---------------- split-K reduce (+bias, +relu) ----------------
__global__ __launch_bounds__(256) void reduce_kernel(
    const float* __restrict__ Cp, float* __restrict__ out, const float* __restrict__ bias,
    int relu, int MN, int N, int sk) {
  int idx = blockIdx.x * 256 + threadIdx.x;
  if (idx >= MN) return;
  float s = 0.f;
  for (int z = 0; z < sk; z++) s += Cp[(size_t)z * MN + idx];
  if (bias) s += bias[idx % N];
  if (relu) s = fmaxf(s, 0.f);
  out[idx] = s;
}

// ---------------- frames: quat->rot, apply rot+trsl to qp/kp/vp ----------------
__global__ __launch_bounds__(64) void frames_kernel(
    const float* __restrict__ proj, const float* __restrict__ quat, const float* __restrict__ trsl,
    float* __restrict__ rotb, float* __restrict__ qpg, float* __restrict__ kpg,
    float* __restrict__ vpg) {
  int i = blockIdx.x, t = threadIdx.x;
  float q0 = quat[i*3+0], q1 = quat[i*3+1], q2 = quat[i*3+2];
  float inv = rsqrtf(1.f + q0*q0 + q1*q1 + q2*q2);
  float w = inv, x = q0*inv, y = q1*inv, z = q2*inv;
  float R00 = 1.f - 2.f*(y*y + z*z), R01 = 2.f*(x*y - w*z), R02 = 2.f*(x*z + w*y);
  float R10 = 2.f*(x*y + w*z), R11 = 1.f - 2.f*(x*x + z*z), R12 = 2.f*(y*z - w*x);
  float R20 = 2.f*(x*z - w*y), R21 = 2.f*(y*z + w*x), R22 = 1.f - 2.f*(x*x + y*y);
  float t0 = trsl[i*3+0], t1 = trsl[i*3+1], t2 = trsl[i*3+2];
  if (t == 0) {
    float* rb = rotb + i*9;
    rb[0]=R00; rb[1]=R01; rb[2]=R02; rb[3]=R10; rb[4]=R11; rb[5]=R12; rb[6]=R20; rb[7]=R21; rb[8]=R22;
  }
  for (int pt = t; pt < 192; pt += 64) {
    const float* src; float* dst;
    if (pt < 48)      { src = proj + i*1152 + 576 + pt*3;        dst = qpg + i*144 + pt*3; }
    else if (pt < 96) { src = proj + i*1152 + 720 + (pt-48)*3;   dst = kpg + i*144 + (pt-48)*3; }
    else              { src = proj + i*1152 + 864 + (pt-96)*3;   dst = vpg + i*288 + (pt-96)*3; }
    float p0 = src[0], p1 = src[1], p2 = src[2];
    dst[0] = R00*p0 + R01*p1 + R02*p2 + t0;
    dst[1] = R10*p0 + R11*p1 + R12*p2 + t1;
    dst[2] = R20*p0 + R21*p1 + R22*p2 + t2;
  }
}

// ---------------- b = pfea @ Wb via bf16 MFMA (M=262144, K=256, N=12 pad 16) -----
__global__ __launch_bounds__(256) void b_mfma_kernel(
    const float* __restrict__ pfea, const float* __restrict__ Wb, float* __restrict__ bmat) {
  __shared__ short wbf[8][64][8];   // per k-step, per lane, 8 bf16 B-frag
  int t = threadIdx.x;
  for (int s = t; s < 512; s += 256) {
    int ks = s >> 6, l = s & 63;
    int col = l & 15, kb = ks * 32 + ((l >> 4) << 3);
    #pragma unroll
    for (int j = 0; j < 8; j++)
      wbf[ks][l][j] = (col < 12) ? (short)rne_bf16(Wb[(kb + j) * 12 + col]) : (short)0;
  }
  __syncthreads();
  int wv = t >> 6, lane = t & 63;
  int wglob = blockIdx.x * 4 + wv;
  int row = lane & 15, kq = lane >> 4;
  for (int it = 0; it < 4; it++) {
    int tile = wglob * 4 + it;
    size_t p0 = (size_t)tile * 16;
    const float* Ab = pfea + (p0 + row) * 256 + kq * 8;
    f32x4 acc = {0.f, 0.f, 0.f, 0.f};
    #pragma unroll
    for (int ks = 0; ks < 8; ks++) {
      float4 f0 = *(const float4*)(Ab + ks * 32);
      float4 f1 = *(const float4*)(Ab + ks * 32 + 4);
      short8 af;
      af[0] = (short)rne_bf16(f0.x); af[1] = (short)rne_bf16(f0.y);
      af[2] = (short)rne_bf16(f0.z); af[3] = (short)rne_bf16(f0.w);
      af[4] = (short)rne_bf16(f1.x); af[5] = (short)rne_bf16(f1.y);
      af[6] = (short)rne_bf16(f1.z); af[7] = (short)rne_bf16(f1.w);
      short8 bfv = *(const short8*)(&wbf[ks][lane][0]);
      acc = __builtin_amdgcn_mfma_f32_16x16x32_bf16(af, bfv, acc, 0, 0, 0);
    }
    int col = lane & 15;
    if (col < 12) {
      #pragma unroll
      for (int r = 0; r < 4; r++) {
        size_t pr = p0 + kq * 4 + r;   // C row = (lane>>4)*4 + reg
        bmat[pr * 12 + col] = acc[r];
      }
    }
  }
}

// ---------------- attention: one block per query row i ----------------
__global__ __launch_bounds__(768) void attn_kernel(
    const float* __restrict__ proj, const float* __restrict__ qpg,
    const float* __restrict__ kpg, const float* __restrict__ vpg,
    const float* __restrict__ bmat, const float* __restrict__ pfea,
    const float* __restrict__ rotb, const float* __restrict__ trsl,
    const float* __restrict__ scale, float* __restrict__ shid) {
  int i = blockIdx.x;
  int t = threadIdx.x;
  __shared__ float Ll[12][512];
  __shared__ float qs[12][16];
  __shared__ float qps[12][12];
  __shared__ float coefs[12];
  __shared__ float ovpg_l[12][24];
  __shared__ float rot_s[9];

  for (int idx = t; idx < 192; idx += 768) qs[idx >> 4][idx & 15] = proj[i*1152 + idx];
  for (int idx = t; idx < 144; idx += 768) qps[idx / 12][idx % 12] = qpg[i*144 + idx];
  if (t < 12) coefs[t] = WC_CONST * 0.5f * log1pf(__expf(scale[t]));
  if (t < 9)  rot_s[t] = rotb[i*9 + t];
  __syncthreads();

  // Phase A: logits
  for (int idx = t; idx < 6144; idx += 768) {
    int h = idx % 12, j = idx / 12;
    const float4* kr = (const float4*)(proj + j*1152 + 192 + h*16);
    const float4* qr = (const float4*)(&qs[h][0]);
    float qk = 0.f;
    #pragma unroll
    for (int m = 0; m < 4; m++) {
      float4 kv = kr[m], qv = qr[m];
      qk += qv.x*kv.x + qv.y*kv.y + qv.z*kv.z + qv.w*kv.w;
    }
    const float4* kpr = (const float4*)(kpg + j*144 + h*12);
    const float4* qpr = (const float4*)(&qps[h][0]);
    float d2 = 0.f;
    #pragma unroll
    for (int m = 0; m < 3; m++) {
      float4 kv = kpr[m], qv = qpr[m];
      float dx = qv.x-kv.x, dy = qv.y-kv.y, dz = qv.z-kv.z, dw = qv.w-kv.w;
      d2 += dx*dx + dy*dy + dz*dz + dw*dw;
    }
    Ll[h][j] = WL_CONST * (qk*0.25f + bmat[(size_t)(i*512 + j)*12 + h] - coefs[h]*d2);
  }
  __syncthreads();

  // Phase B: per-wave softmax (wave w owns head w)
  int w = t >> 6, lane = t & 63;
  {
    float vals[8];
    float m = -1e30f;
    #pragma unroll
    for (int r = 0; r < 8; r++) { vals[r] = Ll[w][lane + (r<<6)]; m = fmaxf(m, vals[r]); }
    #pragma unroll
    for (int off = 32; off >= 1; off >>= 1) m = fmaxf(m, __shfl_xor(m, off));
    float s = 0.f;
    #pragma unroll
    for (int r = 0; r < 8; r++) { vals[r] = __expf(vals[r] - m); s += vals[r]; }
    #pragma unroll
    for (int off = 32; off >= 1; off >>= 1) s += __shfl_xor(s, off);
    float invs = 1.0f / s;
    #pragma unroll
    for (int r = 0; r < 8; r++) Ll[w][lane + (r<<6)] = vals[r] * invs;
  }
  __syncthreads();

  // Phase C: op[h][p] = sum_j a[h][j] * pfea[i][j][p]
  {
    float4 acc = {0.f, 0.f, 0.f, 0.f};
    const float* pf = pfea + (size_t)i * 131072 + (lane << 2);
    #pragma unroll 2
    for (int j = 0; j < 512; j += 4) {
      float4 av = *(const float4*)&Ll[w][j];
      const float* pj = pf + (size_t)j * 256;
      float4 r0 = *(const float4*)(pj);
      float4 r1 = *(const float4*)(pj + 256);
      float4 r2 = *(const float4*)(pj + 512);
      float4 r3 = *(const float4*)(pj + 768);
      acc.x += av.x*r0.x + av.y*r1.x + av.z*r2.x + av.w*r3.x;
      acc.y += av.x*r0.y + av.y*r1.y + av.z*r2.y + av.w*r3.y;
      acc.z += av.x*r0.z + av.y*r1.z + av.z*r2.z + av.w*r3.z;
      acc.w += av.x*r0.w + av.y*r1.w + av.z*r2.w + av.w*r3.w;
    }
    *(float4*)(shid + (size_t)i*3648 + w*304 + (lane << 2)) = acc;
  }

  // Phase D: ov (t<192) and ovp_g (256<=t<544)
  if (t < 192) {
    int h = t >> 4, d = t & 15;
    const float* vb = proj + 384 + h*16 + d;
    float acc = 0.f;
    #pragma unroll 8
    for (int j = 0; j < 512; j++) acc += Ll[h][j] * vb[(size_t)j * 1152];
    shid[(size_t)i*3648 + h*304 + 256 + d] = acc;
  } else if (t >= 256 && t < 544) {
    int idx = t - 256, h = idx / 24, m2 = idx % 24;
    const float* vb = vpg + h*24 + m2;
    float acc = 0.f;
    #pragma unroll 8
    for (int j = 0; j < 512; j++) acc += Ll[h][j] * vb[(size_t)j * 288];
    ovpg_l[h][m2] = acc;
  }
  __syncthreads();

  // Phase E: ovp = rot^T (ovp_g - t), plus norms
  if (t < 96) {
    int h = t >> 3, vv = t & 7;
    float x = ovpg_l[h][vv*3+0] - trsl[i*3+0];
    float y = ovpg_l[h][vv*3+1] - trsl[i*3+1];
    float z = ovpg_l[h][vv*3+2] - trsl[i*3+2];
    float o0 = rot_s[0]*x + rot_s[3]*y + rot_s[6]*z;
    float o1 = rot_s[1]*x + rot_s[4]*y + rot_s[7]*z;
    float o2 = rot_s[2]*x + rot_s[5]*y + rot_s[8]*z;
    float* so = shid + (size_t)i*3648 + h*304 + 272 + vv*3;
    so[0] = o0; so[1] = o1; so[2] = o2;
    shid[(size_t)i*3648 + h*304 + 296 + vv] = sqrtf(o0*o0 + o1*o1 + o2*o2);
  }
}

// ---------------- LayerNorm over 384: out = LN(resid + C + bias)*g + be ----------
__global__ __launch_bounds__(384) void ln384_kernel(
    const float* __restrict__ resid, const float* __restrict__ C, const float* __restrict__ bias,
    const float* __restrict__ g, const float* __restrict__ be, float* __restrict__ out) {
  int i = blockIdx.x, t = threadIdx.x;
  __shared__ float red[6];
  float x = resid[(size_t)i*384 + t] + C[(size_t)i*384 + t] + bias[t];
  float s = x;
  #pragma unroll
  for (int off = 32; off >= 1; off >>= 1) s += __shfl_xor(s, off);
  if ((t & 63) == 0) red[t >> 6] = s;
  __syncthreads();
  float m = (red[0]+red[1]+red[2]+red[3]+red[4]+red[5]) * (1.f/384.f);
  __syncthreads();
  float d = x - m;
  float v = d * d;
  #pragma unroll
  for (int off = 32; off >= 1; off >>= 1) v += __shfl_xor(v, off);
  if ((t & 63) == 0) red[t >> 6] = v;
  __syncthreads();
  float var = (red[0]+red[1]+red[2]+red[3]+red[4]+red[5]) * (1.f/384.f);
  out[(size_t)i*384 + t] = d * rsqrtf(var + 1e-5f) * g[t] + be[t];
}

// ---------------- launcher ----------------
extern "C" void kernel_launch(void* const* d_in, const int* in_sizes, int n_in,
                              void* d_out, int out_size, void* d_ws, size_t ws_size,
                              hipStream_t stream) {
  const float* sfea = (const float*)d_in[0];
  const float* pfea = (const float*)d_in[1];
  const float* quat = (const float*)d_in[2];
  const float* trsl = (const float*)d_in[3];
  const float* Wq   = (const float*)d_in[4];
  const float* Wk   = (const float*)d_in[5];
  const float* Wv   = (const float*)d_in[6];
  const float* Wqp  = (const float*)d_in[7];
  const float* Wkp  = (const float*)d_in[8];
  const float* Wvp  = (const float*)d_in[9];
  const float* Wb   = (const float*)d_in[10];
  const float* scale= (const float*)d_in[11];
  const float* Wsm  = (const float*)d_in[12];
  const float* bs   = (const float*)d_in[13];
  const float* W1   = (const float*)d_in[14];
  const float* b1   = (const float*)d_in[15];
  const float* W2   = (const float*)d_in[16];
  const float* b2   = (const float*)d_in[17];
  const float* W3   = (const float*)d_in[18];
  const float* b3   = (const float*)d_in[19];
  const float* g1   = (const float*)d_in[20];
  const float* be1  = (const float*)d_in[21];
  const float* g2   = (const float*)d_in[22];
  const float* be2  = (const float*)d_in[23];
  float* out = (float*)d_out;
  float* wsf = (float*)d_ws;

  float* Wcat = wsf;                     // 442368
  float* proj = Wcat + 442368;           // 589824
  float* rotb = proj + 589824;           // 4608
  float* qpg  = rotb + 4608;             // 73728
  float* kpg  = qpg + 73728;             // 73728
  float* vpg  = kpg + 73728;             // 147456
  float* bmat = vpg + 147456;            // 3145728
  float* shid = bmat + 3145728;          // 1867776
  float* cpart= shid + 1867776;          // 1179648
  float* C1   = cpart + 1179648;         // 196608
  float* s1   = C1 + 196608;             // 196608
  float* h1   = s1 + 196608;             // 196608
  float* h2   = h1 + 196608;             // 196608
  float* C3   = h2 + 196608;             // 196608 -> total 8507904 floats (~34 MB)

  concat_w_kernel<<<1728, 256, 0, stream>>>(Wq, Wk, Wv, Wqp, Wkp, Wvp, Wcat);
  gemm64_kernel<<<dim3(18, 8, 1), 256, 0, stream>>>(sfea, Wcat, proj, 512, 1152, 384, 384);
  frames_kernel<<<512, 64, 0, stream>>>(proj, quat, trsl, rotb, qpg, kpg, vpg);
  b_mfma_kernel<<<1024, 256, 0, stream>>>(pfea, Wb, bmat);
  attn_kernel<<<512, 768, 0, stream>>>(proj, qpg, kpg, vpg, bmat, pfea, rotb, trsl, scale, shid);

  gemm64_kernel<<<dim3(6, 8, 6), 256, 0, stream>>>(shid, Wsm, cpart, 512, 384, 3648, 608);
  reduce_kernel<<<768, 256, 0, stream>>>(cpart, C1, nullptr, 0, 196608, 384, 6);
  ln384_kernel<<<512, 384, 0, stream>>>(sfea, C1, bs, g1, be1, s1);

  gemm64_kernel<<<dim3(6, 8, 3), 256, 0, stream>>>(s1, W1, cpart, 512, 384, 384, 128);
  reduce_kernel<<<768, 256, 0, stream>>>(cpart, h1, b1, 1, 196608, 384, 3);
  gemm64_kernel<<<dim3(6, 8, 3), 256, 0, stream>>>(h1, W2, cpart, 512, 384, 384, 128);
  reduce_kernel<<<768, 256, 0, stream>>>(cpart, h2, b2, 1, 196608, 384, 3);
  gemm64_kernel<<<dim3(6, 8, 3), 256, 0, stream>>>(h2, W3, cpart, 512, 384, 384, 128);
  reduce_kernel<<<768, 256, 0, stream>>>(cpart, C3, nullptr, 0, 196608, 384, 3);
  ln384_kernel<<<512, 384, 0, stream>>>(s1, C3, b3, g2, be2, out);
}

// Round 2
// 308.045 us; speedup vs baseline: 1.1880x; 1.1880x over previous
//
#include <hip/hip_runtime.h>
#include <cstddef>

typedef __attribute__((ext_vector_type(8))) short short8;
typedef __attribute__((ext_vector_type(4))) float f32x4;

#define WC_CONST 0.2357022603955158f   // sqrt(2/(9*4))
#define WL_CONST 0.5773502691896258f   // sqrt(1/3)

__device__ __forceinline__ unsigned short rne_bf16(float f) {
  unsigned int u = __float_as_uint(f);
  u += 0x7fffu + ((u >> 16) & 1u);
  return (unsigned short)(u >> 16);
}

// ---------------- concat projection weights into [384][1152] ----------------
__global__ __launch_bounds__(256) void concat_w_kernel(
    const float* __restrict__ Wq, const float* __restrict__ Wk, const float* __restrict__ Wv,
    const float* __restrict__ Wqp, const float* __restrict__ Wkp, const float* __restrict__ Wvp,
    float* __restrict__ Wcat) {
  int idx = blockIdx.x * 256 + threadIdx.x;
  if (idx >= 384 * 1152) return;
  int k = idx / 1152, c = idx % 1152;
  float v;
  if (c < 192)       v = Wq [k*192 + c];
  else if (c < 384)  v = Wk [k*192 + (c-192)];
  else if (c < 576)  v = Wv [k*192 + (c-384)];
  else if (c < 720)  v = Wqp[k*144 + (c-576)];
  else if (c < 864)  v = Wkp[k*144 + (c-720)];
  else               v = Wvp[k*288 + (c-864)];
  Wcat[idx] = v;
}

// ---------------- generic fp32 tiled GEMM, 64x64 tile, split-K ----------------
__global__ __launch_bounds__(256) void gemm64_kernel(
    const float* __restrict__ Amat, const float* __restrict__ Bmat, float* __restrict__ Cp,
    int M, int N, int K, int ksl) {
  __shared__ float As[16][68];
  __shared__ float Bs[16][68];
  int t = threadIdx.x;
  int bn = blockIdx.x, bm = blockIdx.y, bz = blockIdx.z;
  int k0 = bz * ksl;
  int tr = t >> 4, tc = t & 15;
  int lm = t >> 2, lk4 = (t & 3) << 2;
  int lkb = t >> 4, lnq = (t & 15) << 2;
  const float* Ab = Amat + (size_t)(bm*64 + lm) * K;
  const float* Bb = Bmat + bn*64 + lnq;
  float acc[4][4];
  #pragma unroll
  for (int a2 = 0; a2 < 4; a2++)
    #pragma unroll
    for (int b2 = 0; b2 < 4; b2++) acc[a2][b2] = 0.f;

  for (int k = k0; k < k0 + ksl; k += 16) {
    float4 av = *(const float4*)(Ab + k + lk4);
    float4 bv = *(const float4*)(Bb + (size_t)(k + lkb) * N);
    As[lk4+0][lm] = av.x; As[lk4+1][lm] = av.y; As[lk4+2][lm] = av.z; As[lk4+3][lm] = av.w;
    *(float4*)&Bs[lkb][lnq] = bv;
    __syncthreads();
    #pragma unroll
    for (int kk = 0; kk < 16; kk++) {
      float4 a4 = *(const float4*)&As[kk][tr << 2];
      float4 b4 = *(const float4*)&Bs[kk][tc << 2];
      float ar[4] = {a4.x, a4.y, a4.z, a4.w};
      float br[4] = {b4.x, b4.y, b4.z, b4.w};
      #pragma unroll
      for (int a2 = 0; a2 < 4; a2++)
        #pragma unroll
        for (int b2 = 0; b2 < 4; b2++) acc[a2][b2] += ar[a2] * br[b2];
    }
    __syncthreads();
  }
  float* Cb = Cp + (size_t)bz * M * N + (size_t)(bm*64 + (tr << 2)) * N + bn*64 + (tc << 2);
  #pragma unroll
  for (int r = 0; r < 4; r++) {
    float4 o = {acc[r][0], acc[r][1], acc[r][2], acc[r][3]};
    *(float4*)(Cb + (size_t)r * N) = o;
  }
}

// ---------------- split-K reduce (+bias, +relu) ----------------
__global__ __launch_bounds__(256) void reduce_kernel(
    const float* __restrict__ Cp, float* __restrict__ out, const float* __restrict__ bias,
    int relu, int MN, int N, int sk) {
  int idx = blockIdx.x * 256 + threadIdx.x;
  if (idx >= MN) return;
  float s = 0.f;
  for (int z = 0; z < sk; z++) s += Cp[(size_t)z * MN + idx];
  if (bias) s += bias[idx % N];
  if (relu) s = fmaxf(s, 0.f);
  out[idx] = s;
}

// ---------------- frames ----------------
__global__ __launch_bounds__(64) void frames_kernel(
    const float* __restrict__ proj, const float* __restrict__ quat, const float* __restrict__ trsl,
    float* __restrict__ rotb, float* __restrict__ qpg, float* __restrict__ kpg,
    float* __restrict__ vpg) {
  int i = blockIdx.x, t = threadIdx.x;
  float q0 = quat[i*3+0], q1 = quat[i*3+1], q2 = quat[i*3+2];
  float inv = rsqrtf(1.f + q0*q0 + q1*q1 + q2*q2);
  float w = inv, x = q0*inv, y = q1*inv, z = q2*inv;
  float R00 = 1.f - 2.f*(y*y + z*z), R01 = 2.f*(x*y - w*z), R02 = 2.f*(x*z + w*y);
  float R10 = 2.f*(x*y + w*z), R11 = 1.f - 2.f*(x*x + z*z), R12 = 2.f*(y*z - w*x);
  float R20 = 2.f*(x*z - w*y), R21 = 2.f*(y*z + w*x), R22 = 1.f - 2.f*(x*x + y*y);
  float t0 = trsl[i*3+0], t1 = trsl[i*3+1], t2 = trsl[i*3+2];
  if (t == 0) {
    float* rb = rotb + i*9;
    rb[0]=R00; rb[1]=R01; rb[2]=R02; rb[3]=R10; rb[4]=R11; rb[5]=R12; rb[6]=R20; rb[7]=R21; rb[8]=R22;
  }
  for (int pt = t; pt < 192; pt += 64) {
    const float* src; float* dst;
    if (pt < 48)      { src = proj + i*1152 + 576 + pt*3;        dst = qpg + i*144 + pt*3; }
    else if (pt < 96) { src = proj + i*1152 + 720 + (pt-48)*3;   dst = kpg + i*144 + (pt-48)*3; }
    else              { src = proj + i*1152 + 864 + (pt-96)*3;   dst = vpg + i*288 + (pt-96)*3; }
    float p0 = src[0], p1 = src[1], p2 = src[2];
    dst[0] = R00*p0 + R01*p1 + R02*p2 + t0;
    dst[1] = R10*p0 + R11*p1 + R12*p2 + t1;
    dst[2] = R20*p0 + R21*p1 + R22*p2 + t2;
  }
}

// ---------------- logit (qk/4 - coef*d2) helper ----------------
__device__ __forceinline__ float lt1_val(
    const float* __restrict__ proj, const float* __restrict__ kpg,
    const float* qs_, const float* qps_, float coef, int jg, int h) {
  const float4* kr = (const float4*)(proj + (size_t)jg*1152 + 192 + h*16);
  const float4* qr = (const float4*)(qs_ + h*16);
  float qk = 0.f;
  #pragma unroll
  for (int m = 0; m < 4; m++) {
    float4 kv = kr[m], qv = qr[m];
    qk += qv.x*kv.x + qv.y*kv.y + qv.z*kv.z + qv.w*kv.w;
  }
  const float4* kpr = (const float4*)(kpg + (size_t)jg*144 + h*12);
  const float4* qpr = (const float4*)(qps_ + h*12);
  float d2 = 0.f;
  #pragma unroll
  for (int m = 0; m < 3; m++) {
    float4 kv = kpr[m], qv = qpr[m];
    float dx = qv.x-kv.x, dy = qv.y-kv.y, dz = qv.z-kv.z, dw = qv.w-kv.w;
    d2 += dx*dx + dy*dy + dz*dz + dw*dw;
  }
  return qk*0.25f - coef*d2;
}

// ---------------- fused single-pass attention (b inline, no-max softmax) -----
// 768 threads = 12 waves. Roles: waves 0-1 MFMA(b), 2-7 logits, 8-11 staging.
__global__ __launch_bounds__(768) void attn2_kernel(
    const float* __restrict__ proj, const float* __restrict__ qpg,
    const float* __restrict__ kpg, const float* __restrict__ vpg,
    const float* __restrict__ pfea, const float* __restrict__ Wb,
    const float* __restrict__ rotb, const float* __restrict__ trsl,
    const float* __restrict__ scale, float* __restrict__ shid) {
  __shared__ __align__(16) float P[32][260];      // pfea tile, padded rows
  __shared__ __align__(16) float Lw[512][12];     // unnormalized exp weights [j][h]
  __shared__ short wbf[8][64][8];                 // Wb bf16 MFMA B-frags
  __shared__ float Lb[2][32][12];                 // qk/4 - coef*d2, double-buffered
  __shared__ __align__(16) float qs[12][16];
  __shared__ __align__(16) float qps[12][12];
  __shared__ float coefs[12];
  __shared__ float sh_inv[12];
  __shared__ float rot_s[9];
  __shared__ float ovpg_l[12][24];

  int i = blockIdx.x;
  int t = threadIdx.x;
  int w = t >> 6, lane = t & 63;

  // ---- init small LDS ----
  for (int idx = t; idx < 192; idx += 768) qs[idx >> 4][idx & 15] = proj[i*1152 + idx];
  for (int idx = t; idx < 144; idx += 768) qps[idx / 12][idx % 12] = qpg[i*144 + idx];
  if (t < 12) coefs[t] = WC_CONST * 0.5f * log1pf(__expf(scale[t]));
  if (t < 9)  rot_s[t] = rotb[i*9 + t];
  for (int s2 = t; s2 < 512; s2 += 768) {
    int ks = s2 >> 6, l = s2 & 63;
    int col = l & 15, kb = ks * 32 + ((l >> 4) << 3);
    #pragma unroll
    for (int j = 0; j < 8; j++)
      wbf[ks][l][j] = (col < 12) ? (short)rne_bf16(Wb[(kb + j) * 12 + col]) : (short)0;
  }
  __syncthreads();

  float4 opacc[12];
  #pragma unroll
  for (int h = 0; h < 12; h++) { opacc[h].x = 0.f; opacc[h].y = 0.f; opacc[h].z = 0.f; opacc[h].w = 0.f; }
  float4 streg[8];

  // ---- prologue: stage loads(0), logits(0) ----
  if (w >= 8) {
    int rbase = (w - 8) * 8;
    const float* src = pfea + (size_t)i * 131072;
    #pragma unroll
    for (int q2 = 0; q2 < 8; q2++)
      streg[q2] = *(const float4*)(src + (size_t)(rbase + q2) * 256 + (lane << 2));
  } else if (w >= 2) {
    int e = (w - 2) * 64 + lane;     // 0..383
    int jl = e / 12, h = e - jl * 12;
    Lb[0][jl][h] = lt1_val(proj, kpg, &qs[0][0], &qps[0][0], coefs[h], jl, h);
  }

  // ---- main loop over 16 tiles of 32 rows ----
  for (int tt = 0; tt < 16; tt++) {
    __syncthreads();   // P free (prev op-accum done); Lb[tt&1] visible
    if (w >= 8) {
      int rbase = (w - 8) * 8;
      #pragma unroll
      for (int q2 = 0; q2 < 8; q2++)
        *(float4*)&P[rbase + q2][lane << 2] = streg[q2];
    }
    __syncthreads();   // P(tt) visible
    if (w < 2) {
      // b via MFMA from LDS, then finalize weights for this tile
      f32x4 accb = {0.f, 0.f, 0.f, 0.f};
      int row = (w << 4) + (lane & 15);
      int kq = lane >> 4;
      const float* Pb = &P[row][kq * 8];
      #pragma unroll
      for (int ks = 0; ks < 8; ks++) {
        float4 f0 = *(const float4*)(Pb + ks * 32);
        float4 f1 = *(const float4*)(Pb + ks * 32 + 4);
        short8 af;
        af[0] = (short)rne_bf16(f0.x); af[1] = (short)rne_bf16(f0.y);
        af[2] = (short)rne_bf16(f0.z); af[3] = (short)rne_bf16(f0.w);
        af[4] = (short)rne_bf16(f1.x); af[5] = (short)rne_bf16(f1.y);
        af[6] = (short)rne_bf16(f1.z); af[7] = (short)rne_bf16(f1.w);
        short8 bfv = *(const short8*)(&wbf[ks][lane][0]);
        accb = __builtin_amdgcn_mfma_f32_16x16x32_bf16(af, bfv, accb, 0, 0, 0);
      }
      int h = lane & 15;
      if (h < 12) {
        #pragma unroll
        for (int r = 0; r < 4; r++) {
          int jl = (w << 4) + kq * 4 + r;
          float lv = Lb[tt & 1][jl][h] + accb[r];
          Lw[tt * 32 + jl][h] = __expf(WL_CONST * lv);
        }
      }
    } else if (w < 8) {
      if (tt < 15) {
        int e = (w - 2) * 64 + lane;
        int jl = e / 12, h = e - jl * 12;
        Lb[(tt + 1) & 1][jl][h] =
            lt1_val(proj, kpg, &qs[0][0], &qps[0][0], coefs[h], (tt + 1) * 32 + jl, h);
      }
    } else {
      if (tt < 15) {
        int rbase = (w - 8) * 8;
        const float* src = pfea + (size_t)i * 131072 + (size_t)(tt + 1) * 32 * 256;
        #pragma unroll
        for (int q2 = 0; q2 < 8; q2++)
          streg[q2] = *(const float4*)(src + (size_t)(rbase + q2) * 256 + (lane << 2));
      }
    }
    __syncthreads();   // Lw(tt) visible
    // op accumulation: each wave owns rows r%12==w of the tile
    for (int rr = w; rr < 32; rr += 12) {
      const float4* lwp = (const float4*)&Lw[tt * 32 + rr][0];
      float4 wa = lwp[0], wb2 = lwp[1], wc = lwp[2];
      float4 pv = *(const float4*)&P[rr][lane << 2];
      opacc[0].x += pv.x*wa.x; opacc[0].y += pv.y*wa.x; opacc[0].z += pv.z*wa.x; opacc[0].w += pv.w*wa.x;
      opacc[1].x += pv.x*wa.y; opacc[1].y += pv.y*wa.y; opacc[1].z += pv.z*wa.y; opacc[1].w += pv.w*wa.y;
      opacc[2].x += pv.x*wa.z; opacc[2].y += pv.y*wa.z; opacc[2].z += pv.z*wa.z; opacc[2].w += pv.w*wa.z;
      opacc[3].x += pv.x*wa.w; opacc[3].y += pv.y*wa.w; opacc[3].z += pv.z*wa.w; opacc[3].w += pv.w*wa.w;
      opacc[4].x += pv.x*wb2.x; opacc[4].y += pv.y*wb2.x; opacc[4].z += pv.z*wb2.x; opacc[4].w += pv.w*wb2.x;
      opacc[5].x += pv.x*wb2.y; opacc[5].y += pv.y*wb2.y; opacc[5].z += pv.z*wb2.y; opacc[5].w += pv.w*wb2.y;
      opacc[6].x += pv.x*wb2.z; opacc[6].y += pv.y*wb2.z; opacc[6].z += pv.z*wb2.z; opacc[6].w += pv.w*wb2.z;
      opacc[7].x += pv.x*wb2.w; opacc[7].y += pv.y*wb2.w; opacc[7].z += pv.z*wb2.w; opacc[7].w += pv.w*wb2.w;
      opacc[8].x += pv.x*wc.x; opacc[8].y += pv.y*wc.x; opacc[8].z += pv.z*wc.x; opacc[8].w += pv.w*wc.x;
      opacc[9].x += pv.x*wc.y; opacc[9].y += pv.y*wc.y; opacc[9].z += pv.z*wc.y; opacc[9].w += pv.w*wc.y;
      opacc[10].x += pv.x*wc.z; opacc[10].y += pv.y*wc.z; opacc[10].z += pv.z*wc.z; opacc[10].w += pv.w*wc.z;
      opacc[11].x += pv.x*wc.w; opacc[11].y += pv.y*wc.w; opacc[11].z += pv.z*wc.w; opacc[11].w += pv.w*wc.w;
    }
  }
  __syncthreads();

  // ---- s[h] = sum_j w  ->  sh_inv ----
  if (w < 12) {
    float sacc = 0.f;
    #pragma unroll
    for (int r2 = 0; r2 < 8; r2++) sacc += Lw[r2 * 64 + lane][w];
    #pragma unroll
    for (int off = 32; off >= 1; off >>= 1) sacc += __shfl_xor(sacc, off);
    if (lane == 0) sh_inv[w] = 1.0f / sacc;
  }
  __syncthreads();

  // ---- op cross-wave reduce (6 rounds of 2 heads), write to shid ----
  float4* Pred = (float4*)&P[0][0];
  #pragma unroll
  for (int gr = 0; gr < 6; gr++) {
    Pred[(w * 2 + 0) * 64 + lane] = opacc[2 * gr + 0];
    Pred[(w * 2 + 1) * 64 + lane] = opacc[2 * gr + 1];
    __syncthreads();
    if (t < 128) {
      int hh = t >> 6, ll = t & 63;
      float4 sum = {0.f, 0.f, 0.f, 0.f};
      #pragma unroll
      for (int w2 = 0; w2 < 12; w2++) {
        float4 v = Pred[(w2 * 2 + hh) * 64 + ll];
        sum.x += v.x; sum.y += v.y; sum.z += v.z; sum.w += v.w;
      }
      int h = 2 * gr + hh;
      float isv = sh_inv[h];
      float4 o = {sum.x * isv, sum.y * isv, sum.z * isv, sum.w * isv};
      *(float4*)(shid + (size_t)i * 3648 + h * 304 + (ll << 2)) = o;
    }
    __syncthreads();
  }

  // ---- ov and ovp_g ----
  if (t < 192) {
    int h = t >> 4, d = t & 15;
    const float* vb = proj + 384 + h * 16 + d;
    float acc = 0.f;
    #pragma unroll 8
    for (int j = 0; j < 512; j++) acc += Lw[j][h] * vb[(size_t)j * 1152];
    shid[(size_t)i * 3648 + h * 304 + 256 + d] = acc * sh_inv[h];
  } else if (t >= 256 && t < 544) {
    int idx = t - 256, h = idx / 24, m2 = idx % 24;
    const float* vb = vpg + h * 24 + m2;
    float acc = 0.f;
    #pragma unroll 8
    for (int j = 0; j < 512; j++) acc += Lw[j][h] * vb[(size_t)j * 288];
    ovpg_l[h][m2] = acc * sh_inv[h];
  }
  __syncthreads();

  // ---- ovp = rot^T (ovp_g - t), norms ----
  if (t < 96) {
    int h = t >> 3, vv = t & 7;
    float x = ovpg_l[h][vv*3+0] - trsl[i*3+0];
    float y = ovpg_l[h][vv*3+1] - trsl[i*3+1];
    float z = ovpg_l[h][vv*3+2] - trsl[i*3+2];
    float o0 = rot_s[0]*x + rot_s[3]*y + rot_s[6]*z;
    float o1 = rot_s[1]*x + rot_s[4]*y + rot_s[7]*z;
    float o2 = rot_s[2]*x + rot_s[5]*y + rot_s[8]*z;
    float* so = shid + (size_t)i*3648 + h*304 + 272 + vv*3;
    so[0] = o0; so[1] = o1; so[2] = o2;
    shid[(size_t)i*3648 + h*304 + 296 + vv] = sqrtf(o0*o0 + o1*o1 + o2*o2);
  }
}

// ---------------- LayerNorm over 384 ----------------
__global__ __launch_bounds__(384) void ln384_kernel(
    const float* __restrict__ resid, const float* __restrict__ C, const float* __restrict__ bias,
    const float* __restrict__ g, const float* __restrict__ be, float* __restrict__ out) {
  int i = blockIdx.x, t = threadIdx.x;
  __shared__ float red[6];
  float x = resid[(size_t)i*384 + t] + C[(size_t)i*384 + t] + bias[t];
  float s = x;
  #pragma unroll
  for (int off = 32; off >= 1; off >>= 1) s += __shfl_xor(s, off);
  if ((t & 63) == 0) red[t >> 6] = s;
  __syncthreads();
  float m = (red[0]+red[1]+red[2]+red[3]+red[4]+red[5]) * (1.f/384.f);
  __syncthreads();
  float d = x - m;
  float v = d * d;
  #pragma unroll
  for (int off = 32; off >= 1; off >>= 1) v += __shfl_xor(v, off);
  if ((t & 63) == 0) red[t >> 6] = v;
  __syncthreads();
  float var = (red[0]+red[1]+red[2]+red[3]+red[4]+red[5]) * (1.f/384.f);
  out[(size_t)i*384 + t] = d * rsqrtf(var + 1e-5f) * g[t] + be[t];
}

// ---------------- launcher ----------------
extern "C" void kernel_launch(void* const* d_in, const int* in_sizes, int n_in,
                              void* d_out, int out_size, void* d_ws, size_t ws_size,
                              hipStream_t stream) {
  const float* sfea = (const float*)d_in[0];
  const float* pfea = (const float*)d_in[1];
  const float* quat = (const float*)d_in[2];
  const float* trsl = (const float*)d_in[3];
  const float* Wq   = (const float*)d_in[4];
  const float* Wk   = (const float*)d_in[5];
  const float* Wv   = (const float*)d_in[6];
  const float* Wqp  = (const float*)d_in[7];
  const float* Wkp  = (const float*)d_in[8];
  const float* Wvp  = (const float*)d_in[9];
  const float* Wb   = (const float*)d_in[10];
  const float* scale= (const float*)d_in[11];
  const float* Wsm  = (const float*)d_in[12];
  const float* bs   = (const float*)d_in[13];
  const float* W1   = (const float*)d_in[14];
  const float* b1   = (const float*)d_in[15];
  const float* W2   = (const float*)d_in[16];
  const float* b2   = (const float*)d_in[17];
  const float* W3   = (const float*)d_in[18];
  const float* b3   = (const float*)d_in[19];
  const float* g1   = (const float*)d_in[20];
  const float* be1  = (const float*)d_in[21];
  const float* g2   = (const float*)d_in[22];
  const float* be2  = (const float*)d_in[23];
  float* out = (float*)d_out;
  float* wsf = (float*)d_ws;

  float* Wcat = wsf;                     // 442368
  float* proj = Wcat + 442368;           // 589824
  float* rotb = proj + 589824;           // 4608
  float* qpg  = rotb + 4608;             // 73728
  float* kpg  = qpg + 73728;             // 73728
  float* vpg  = kpg + 73728;             // 147456
  float* shid = vpg + 147456;            // 1867776
  float* cpart= shid + 1867776;          // 1179648
  float* C1   = cpart + 1179648;         // 196608
  float* s1   = C1 + 196608;             // 196608
  float* h1   = s1 + 196608;             // 196608
  float* h2   = h1 + 196608;             // 196608
  float* C3   = h2 + 196608;             // 196608

  concat_w_kernel<<<1728, 256, 0, stream>>>(Wq, Wk, Wv, Wqp, Wkp, Wvp, Wcat);
  gemm64_kernel<<<dim3(18, 8, 1), 256, 0, stream>>>(sfea, Wcat, proj, 512, 1152, 384, 384);
  frames_kernel<<<512, 64, 0, stream>>>(proj, quat, trsl, rotb, qpg, kpg, vpg);
  attn2_kernel<<<512, 768, 0, stream>>>(proj, qpg, kpg, vpg, pfea, Wb, rotb, trsl, scale, shid);

  gemm64_kernel<<<dim3(6, 8, 6), 256, 0, stream>>>(shid, Wsm, cpart, 512, 384, 3648, 608);
  reduce_kernel<<<768, 256, 0, stream>>>(cpart, C1, nullptr, 0, 196608, 384, 6);
  ln384_kernel<<<512, 384, 0, stream>>>(sfea, C1, bs, g1, be1, s1);

  gemm64_kernel<<<dim3(6, 8, 3), 256, 0, stream>>>(s1, W1, cpart, 512, 384, 384, 128);
  reduce_kernel<<<768, 256, 0, stream>>>(cpart, h1, b1, 1, 196608, 384, 3);
  gemm64_kernel<<<dim3(6, 8, 3), 256, 0, stream>>>(h1, W2, cpart, 512, 384, 384, 128);
  reduce_kernel<<<768, 256, 0, stream>>>(cpart, h2, b2, 1, 196608, 384, 3);
  gemm64_kernel<<<dim3(6, 8, 3), 256, 0, stream>>>(h2, W3, cpart, 512, 384, 384, 128);
  reduce_kernel<<<768, 256, 0, stream>>>(cpart, C3, nullptr, 0, 196608, 384, 3);
  ln384_kernel<<<512, 384, 0, stream>>>(s1, C3, b3, g2, be2, out);
}